// Round 3
// baseline (120.909 us; speedup 1.0000x reference)
//
#include <hip/hip_runtime.h>
#include <math.h>

// Problem constants (fixed by the reference harness)
#define HD      768          // hidden dim H
#define TLEN    512          // seq_len T
#define NCH     8            // NC chunks
#define NNOTE   4            // NN notes
#define ROWK    1115         // full rows of reshaped-weights per chunk
#define F4      192          // HD/4 float4 per row

// Byte-balanced 256-block partition (all blocks 154-160 KB):
//   enc: 80 blocks = 8 chunks x 10 segs; segs 0..7 -> 51 rows, segs 8..9 -> 52 rows
//   lw : 176 blocks = 8 k x 22 segs;     segs 0..14 -> 51 rows, segs 15..21 -> 50 rows
#define ENC_BLOCKS  80
#define ENC_SEGS    10
#define LW_SEGS     22
#define LW_BLOCKS   176
#define NPART       256

// ---------------------------------------------------------------------------
// Kernel A: all the heavy memory traffic (40 MB), byte-balanced, 1 block/CU,
// 192 threads = 3 waves; thread t owns float4 column t. Unchanged from R2
// (measured at its HBM roofline: balancing the partition moved nothing).
// ---------------------------------------------------------------------------
__global__ __launch_bounds__(192) void talc_reduce_kernel(
    const float* __restrict__ enc,
    const float* __restrict__ lw,
    float* __restrict__ ws) {
  const int t = threadIdx.x;          // 0..191
  const int b = blockIdx.x;           // 0..255
  float4* P = (float4*)ws;            // P[256][192] float4

  const float4* base;
  int rn;
  if (b < ENC_BLOCKS) {
    const int c = b / ENC_SEGS, seg = b - c * ENC_SEGS;
    const int start = (seg < 8) ? 51 * seg : 408 + 52 * (seg - 8);
    rn = (seg < 8) ? 51 : 52;
    base = (const float4*)enc + (size_t)(c * TLEN + start) * F4 + t;
  } else {
    const int l = b - ENC_BLOCKS;
    const int k = l / LW_SEGS, seg = l - k * LW_SEGS;
    const int start = (seg < 15) ? 51 * seg : 765 + 50 * (seg - 15);
    rn = (seg < 15) ? 51 : 50;
    base = (const float4*)lw + (size_t)(k * ROWK + start) * F4 + t;
  }

  float4 acc = make_float4(0.f, 0.f, 0.f, 0.f);
#pragma unroll 8
  for (int r = 0; r < rn; ++r) {
    float4 v = base[(size_t)r * F4];
    acc.x += v.x; acc.y += v.y; acc.z += v.z; acc.w += v.w;
  }
  P[(size_t)b * F4 + t] = acc;
}

// ---------------------------------------------------------------------------
// Kernel B: finish, latency-parallelized. 6 blocks x 512 threads.
// tid = sub*128 + hh; sub 0..3 each reduces a quarter of the 256 partial
// rows for h-slice [blockIdx*128, +128), combined via 32 KB LDS. 8 waves/CU
// of MLP instead of 2 (R0-R2 version) to hide the L3-latency P reads.
// Epilogue (sub==0 only):
//   B[c]  = enc 512-block column sums;  Tk[k] = lw 1115-row range sums
//   R[m]  = lwR[1115*m, h] boundary rows
//   G[k]  = R[k]*Esuf[k] + (Tk[k]-R[k])*E + R[k+1]*Epre[k+1]
//   out[n,h] = sigmoid( sum_c Mc[n][c] * G[c] ),  Mc = note-mask softmax table
// ---------------------------------------------------------------------------
__global__ __launch_bounds__(512) void talc_finish_kernel(
    const float* __restrict__ lw,
    const int* __restrict__ ids,
    const float* __restrict__ ws,
    float* __restrict__ out) {
  __shared__ float lds[4][16][128];
  const int tid = threadIdx.x;
  const int sub = tid >> 7;                       // 0..3
  const int hh  = tid & 127;                      // 0..127
  const int h   = blockIdx.x * 128 + hh;          // 0..767
  const float* P = ws;

  // strided quarter-reductions of the 256 partial rows
  float part[16];
#pragma unroll
  for (int i = 0; i < 16; ++i) part[i] = 0.f;
#pragma unroll
  for (int c = 0; c < NCH; ++c)
    for (int g = sub; g < ENC_SEGS; g += 4)
      part[c] += P[(size_t)(c * ENC_SEGS + g) * HD + h];
#pragma unroll
  for (int k = 0; k < NCH; ++k)
    for (int g = sub; g < LW_SEGS; g += 4)
      part[8 + k] += P[(size_t)(ENC_BLOCKS + k * LW_SEGS + g) * HD + h];
#pragma unroll
  for (int i = 0; i < 16; ++i) lds[sub][i][hh] = part[i];
  __syncthreads();
  if (sub != 0) return;

  float B[NCH], Tk[NCH];
#pragma unroll
  for (int c = 0; c < NCH; ++c)
    B[c] = lds[0][c][hh] + lds[1][c][hh] + lds[2][c][hh] + lds[3][c][hh];
#pragma unroll
  for (int k = 0; k < NCH; ++k)
    Tk[k] = lds[0][8 + k][hh] + lds[1][8 + k][hh] + lds[2][8 + k][hh] + lds[3][8 + k][hh];

  float Esuf[NCH + 1];
  Esuf[NCH] = 0.f;
#pragma unroll
  for (int c = NCH - 1; c >= 0; --c) Esuf[c] = Esuf[c + 1] + B[c];
  float Epre[NCH + 1];
  Epre[0] = 0.f;
#pragma unroll
  for (int c = 1; c <= NCH; ++c) Epre[c] = Epre[c - 1] + B[c - 1];
  const float E = Esuf[0];

  // single boundary rows R[m] = lwR[1115*m, h]
  float R[NCH + 1];
#pragma unroll
  for (int m = 0; m <= NCH; ++m) R[m] = lw[(size_t)(m * ROWK) * HD + h];

  float G[NCH];
#pragma unroll
  for (int k = 0; k < NCH; ++k)
    G[k] = R[k] * Esuf[k] + (Tk[k] - R[k]) * E + R[k + 1] * Epre[k + 1];

  int id[NNOTE];
#pragma unroll
  for (int n = 0; n < NNOTE; ++n) id[n] = ids[n];

  float score[NNOTE] = {0.f, 0.f, 0.f, 0.f};
#pragma unroll
  for (int c = 0; c < NCH; ++c) {
    int cnt = 0;
#pragma unroll
    for (int n = 0; n < NNOTE; ++n) cnt += (id[n] + 1 <= c) ? 1 : 0;
    const float inv = (cnt > 0) ? (1.f / (float)cnt) : 0.f;
#pragma unroll
    for (int n = 0; n < NNOTE; ++n) {
      const float m = (cnt == 0) ? 0.25f : (((id[n] + 1) <= c) ? inv : 0.f);
      score[n] += m * G[c];
    }
  }
#pragma unroll
  for (int n = 0; n < NNOTE; ++n)
    out[(size_t)n * HD + h] = 1.f / (1.f + expf(-score[n]));
}

extern "C" void kernel_launch(void* const* d_in, const int* in_sizes, int n_in,
                              void* d_out, int out_size, void* d_ws, size_t ws_size,
                              hipStream_t stream) {
  (void)in_sizes; (void)n_in; (void)out_size; (void)ws_size;
  const float* enc = (const float*)d_in[0];       // (4096, 768)
  // d_in[1] = label_queries — provably unused (softmax over notes is
  // shift-invariant; the identical-across-notes score term cancels exactly).
  const float* lw  = (const float*)d_in[2];       // (768, 8921) buffer, read as (8921, 768)
  const int*   ids = (const int*)d_in[3];         // (4,) note_end_chunk_ids
  float* ws  = (float*)d_ws;                      // 256*768 floats = 786 KB used
  float* out = (float*)d_out;                     // (4, 768) fp32

  talc_reduce_kernel<<<NPART, 192, 0, stream>>>(enc, lw, ws);
  talc_finish_kernel<<<6, 512, 0, stream>>>(lw, ids, ws, out);
}

// Round 4
// 102.155 us; speedup vs baseline: 1.1836x; 1.1836x over previous
//
#include <hip/hip_runtime.h>
#include <math.h>

// Problem constants (fixed by the reference harness)
#define HD      768          // hidden dim H
#define TLEN    512          // seq_len T
#define NCH     8            // NC chunks
#define NNOTE   4            // NN notes
#define ROWK    1115         // full rows of reshaped-weights per chunk
#define F4      192          // HD/4 float4 per row

// Byte-balanced 256-block partition (all blocks 154-160 KB):
//   enc: 80 blocks = 8 chunks x 10 segs; segs 0..7 -> 51 rows, segs 8..9 -> 52 rows
//   lw : 176 blocks = 8 k x 22 segs;     segs 0..14 -> 51 rows, segs 15..21 -> 50 rows
#define ENC_BLOCKS  80
#define ENC_SEGS    10
#define LW_SEGS     22
#define LW_BLOCKS   176
#define NPART       256

// ---------------------------------------------------------------------------
// Kernel A: all the heavy memory traffic (40 MB). 384 threads = 6 waves/CU
// (was 3): rows split by parity between the two 192-thread halves to double
// the outstanding-load count (R2 evidence says A is latency-bound, not
// BW-bound: balancing bytes was neutral). Halves combine via 3 KB LDS; the
// single P row per block is unchanged, so kernel B stays byte-identical to
// the proven R2 version.
// ---------------------------------------------------------------------------
__global__ __launch_bounds__(384) void talc_reduce_kernel(
    const float* __restrict__ enc,
    const float* __restrict__ lw,
    float* __restrict__ ws) {
  const int t  = threadIdx.x;         // 0..383
  const int rg = t / 192;             // row-parity group 0/1
  const int col = t - rg * 192;       // float4 column 0..191
  const int b = blockIdx.x;           // 0..255
  float4* P = (float4*)ws;            // P[256][192] float4

  const float4* base;
  int rn;
  if (b < ENC_BLOCKS) {
    const int c = b / ENC_SEGS, seg = b - c * ENC_SEGS;
    const int start = (seg < 8) ? 51 * seg : 408 + 52 * (seg - 8);
    rn = (seg < 8) ? 51 : 52;
    base = (const float4*)enc + (size_t)(c * TLEN + start) * F4 + col;
  } else {
    const int l = b - ENC_BLOCKS;
    const int k = l / LW_SEGS, seg = l - k * LW_SEGS;
    const int start = (seg < 15) ? 51 * seg : 765 + 50 * (seg - 15);
    rn = (seg < 15) ? 51 : 50;
    base = (const float4*)lw + (size_t)(k * ROWK + start) * F4 + col;
  }

  float4 acc = make_float4(0.f, 0.f, 0.f, 0.f);
#pragma unroll 8
  for (int r = rg; r < rn; r += 2) {
    float4 v = base[(size_t)r * F4];
    acc.x += v.x; acc.y += v.y; acc.z += v.z; acc.w += v.w;
  }

  __shared__ float4 comb[192];        // 3 KB
  if (rg == 1) comb[col] = acc;
  __syncthreads();
  if (rg == 0) {
    float4 o = comb[col];
    acc.x += o.x; acc.y += o.y; acc.z += o.z; acc.w += o.w;
    P[(size_t)b * F4 + col] = acc;
  }
}

// ---------------------------------------------------------------------------
// Kernel B: finish (byte-identical to the proven R0/R2 version).
// 6 blocks x 128 threads, one thread per h.
//   B[c]  = sum of 10 enc partials      (512-block column sums of encoding)
//   Tk[k] = sum of 22 lw partials       (1115-row sums of reshaped weights)
//   R[m]  = lwR[1115*m, h], m=0..8      (boundary rows)
//   G[k]  = R[k]*Esuf[k] + (Tk[k]-R[k])*E + R[k+1]*Epre[k+1]
//   out[n,h] = sigmoid( sum_c Mc[n][c] * G[c] ),  Mc = note-mask softmax table
// ---------------------------------------------------------------------------
__global__ __launch_bounds__(128) void talc_finish_kernel(
    const float* __restrict__ lw,
    const int* __restrict__ ids,
    const float* __restrict__ ws,
    float* __restrict__ out) {
  const int h = blockIdx.x * 128 + threadIdx.x;   // 0..767
  if (h >= HD) return;
  const float* P = ws;

  float B[NCH];
#pragma unroll
  for (int c = 0; c < NCH; ++c) {
    float s = 0.f;
#pragma unroll
    for (int g = 0; g < ENC_SEGS; ++g) s += P[(size_t)(c * ENC_SEGS + g) * HD + h];
    B[c] = s;
  }
  float Esuf[NCH + 1];
  Esuf[NCH] = 0.f;
#pragma unroll
  for (int c = NCH - 1; c >= 0; --c) Esuf[c] = Esuf[c + 1] + B[c];
  float Epre[NCH + 1];
  Epre[0] = 0.f;
#pragma unroll
  for (int c = 1; c <= NCH; ++c) Epre[c] = Epre[c - 1] + B[c - 1];
  const float E = Esuf[0];

  float Tk[NCH];
#pragma unroll
  for (int k = 0; k < NCH; ++k) {
    float s = 0.f;
#pragma unroll
    for (int g = 0; g < LW_SEGS; ++g)
      s += P[(size_t)(ENC_BLOCKS + k * LW_SEGS + g) * HD + h];
    Tk[k] = s;
  }

  // single boundary rows R[m] = lwR[1115*m, h]
  float R[NCH + 1];
#pragma unroll
  for (int m = 0; m <= NCH; ++m) R[m] = lw[(size_t)(m * ROWK) * HD + h];

  float G[NCH];
#pragma unroll
  for (int k = 0; k < NCH; ++k)
    G[k] = R[k] * Esuf[k] + (Tk[k] - R[k]) * E + R[k + 1] * Epre[k + 1];

  int id[NNOTE];
#pragma unroll
  for (int n = 0; n < NNOTE; ++n) id[n] = ids[n];

  float score[NNOTE] = {0.f, 0.f, 0.f, 0.f};
#pragma unroll
  for (int c = 0; c < NCH; ++c) {
    int cnt = 0;
#pragma unroll
    for (int n = 0; n < NNOTE; ++n) cnt += (id[n] + 1 <= c) ? 1 : 0;
    const float inv = (cnt > 0) ? (1.f / (float)cnt) : 0.f;
#pragma unroll
    for (int n = 0; n < NNOTE; ++n) {
      const float m = (cnt == 0) ? 0.25f : (((id[n] + 1) <= c) ? inv : 0.f);
      score[n] += m * G[c];
    }
  }
#pragma unroll
  for (int n = 0; n < NNOTE; ++n) {
    out[(size_t)n * HD + h] = 1.f / (1.f + expf(-score[n]));
  }
}

extern "C" void kernel_launch(void* const* d_in, const int* in_sizes, int n_in,
                              void* d_out, int out_size, void* d_ws, size_t ws_size,
                              hipStream_t stream) {
  (void)in_sizes; (void)n_in; (void)out_size; (void)ws_size;
  const float* enc = (const float*)d_in[0];       // (4096, 768)
  // d_in[1] = label_queries — provably unused (softmax over notes is
  // shift-invariant; the identical-across-notes score term cancels exactly).
  const float* lw  = (const float*)d_in[2];       // (768, 8921) buffer, read as (8921, 768)
  const int*   ids = (const int*)d_in[3];         // (4,) note_end_chunk_ids
  float* ws  = (float*)d_ws;                      // 256*768 floats = 786 KB used
  float* out = (float*)d_out;                     // (4, 768) fp32

  talc_reduce_kernel<<<NPART, 384, 0, stream>>>(enc, lw, ws);
  talc_finish_kernel<<<6, 128, 0, stream>>>(lw, ids, ws, out);
}

// Round 5
// 101.445 us; speedup vs baseline: 1.1919x; 1.0070x over previous
//
#include <hip/hip_runtime.h>
#include <math.h>

// Problem constants (fixed by the reference harness)
#define HD      768          // hidden dim H
#define TLEN    512          // seq_len T
#define NCH     8            // NC chunks
#define NNOTE   4            // NN notes
#define ROWK    1115         // full rows of reshaped-weights per chunk
#define F4      192          // HD/4 float4 per row

// Byte-balanced 256-block partition (all blocks 154-160 KB):
//   enc: 80 blocks = 8 chunks x 10 segs; segs 0..7 -> 51 rows, segs 8..9 -> 52 rows
//   lw : 176 blocks = 8 k x 22 segs;     segs 0..14 -> 51 rows, segs 15..21 -> 50 rows
#define ENC_BLOCKS  80
#define ENC_SEGS    10
#define LW_SEGS     22
#define LW_BLOCKS   176
#define NPART       256

// ---------------------------------------------------------------------------
// Kernel A: all the heavy memory traffic (40 MB). 768 threads = 12 waves/CU
// (R4's 6-wave version proved A latency-bound: 3->6 waves bought 2.33 us at
// identical bytes). Rows split 4-way by residue class among the four
// 192-thread groups; groups combine via 9 KB LDS; single P-row write per
// block unchanged, so kernel B stays byte-identical to the proven version.
// ---------------------------------------------------------------------------
__global__ __launch_bounds__(768) void talc_reduce_kernel(
    const float* __restrict__ enc,
    const float* __restrict__ lw,
    float* __restrict__ ws) {
  const int t   = threadIdx.x;        // 0..767
  const int rg  = t / 192;            // row-residue group 0..3
  const int col = t - rg * 192;       // float4 column 0..191
  const int b = blockIdx.x;           // 0..255
  float4* P = (float4*)ws;            // P[256][192] float4

  const float4* base;
  int rn;
  if (b < ENC_BLOCKS) {
    const int c = b / ENC_SEGS, seg = b - c * ENC_SEGS;
    const int start = (seg < 8) ? 51 * seg : 408 + 52 * (seg - 8);
    rn = (seg < 8) ? 51 : 52;
    base = (const float4*)enc + (size_t)(c * TLEN + start) * F4 + col;
  } else {
    const int l = b - ENC_BLOCKS;
    const int k = l / LW_SEGS, seg = l - k * LW_SEGS;
    const int start = (seg < 15) ? 51 * seg : 765 + 50 * (seg - 15);
    rn = (seg < 15) ? 51 : 50;
    base = (const float4*)lw + (size_t)(k * ROWK + start) * F4 + col;
  }

  float4 acc = make_float4(0.f, 0.f, 0.f, 0.f);
#pragma unroll 4
  for (int r = rg; r < rn; r += 4) {
    float4 v = base[(size_t)r * F4];
    acc.x += v.x; acc.y += v.y; acc.z += v.z; acc.w += v.w;
  }

  __shared__ float4 comb[3][192];     // 9 KB
  if (rg != 0) comb[rg - 1][col] = acc;
  __syncthreads();
  if (rg == 0) {
    float4 a = comb[0][col], bb = comb[1][col], cc = comb[2][col];
    acc.x += a.x + bb.x + cc.x;
    acc.y += a.y + bb.y + cc.y;
    acc.z += a.z + bb.z + cc.z;
    acc.w += a.w + bb.w + cc.w;
    P[(size_t)b * F4 + col] = acc;
  }
}

// ---------------------------------------------------------------------------
// Kernel B: finish (byte-identical to the proven R0/R2/R4 version).
// 6 blocks x 128 threads, one thread per h.
//   B[c]  = sum of 10 enc partials      (512-block column sums of encoding)
//   Tk[k] = sum of 22 lw partials       (1115-row sums of reshaped weights)
//   R[m]  = lwR[1115*m, h], m=0..8      (boundary rows)
//   G[k]  = R[k]*Esuf[k] + (Tk[k]-R[k])*E + R[k+1]*Epre[k+1]
//   out[n,h] = sigmoid( sum_c Mc[n][c] * G[c] ),  Mc = note-mask softmax table
// ---------------------------------------------------------------------------
__global__ __launch_bounds__(128) void talc_finish_kernel(
    const float* __restrict__ lw,
    const int* __restrict__ ids,
    const float* __restrict__ ws,
    float* __restrict__ out) {
  const int h = blockIdx.x * 128 + threadIdx.x;   // 0..767
  if (h >= HD) return;
  const float* P = ws;

  float B[NCH];
#pragma unroll
  for (int c = 0; c < NCH; ++c) {
    float s = 0.f;
#pragma unroll
    for (int g = 0; g < ENC_SEGS; ++g) s += P[(size_t)(c * ENC_SEGS + g) * HD + h];
    B[c] = s;
  }
  float Esuf[NCH + 1];
  Esuf[NCH] = 0.f;
#pragma unroll
  for (int c = NCH - 1; c >= 0; --c) Esuf[c] = Esuf[c + 1] + B[c];
  float Epre[NCH + 1];
  Epre[0] = 0.f;
#pragma unroll
  for (int c = 1; c <= NCH; ++c) Epre[c] = Epre[c - 1] + B[c - 1];
  const float E = Esuf[0];

  float Tk[NCH];
#pragma unroll
  for (int k = 0; k < NCH; ++k) {
    float s = 0.f;
#pragma unroll
    for (int g = 0; g < LW_SEGS; ++g)
      s += P[(size_t)(ENC_BLOCKS + k * LW_SEGS + g) * HD + h];
    Tk[k] = s;
  }

  // single boundary rows R[m] = lwR[1115*m, h]
  float R[NCH + 1];
#pragma unroll
  for (int m = 0; m <= NCH; ++m) R[m] = lw[(size_t)(m * ROWK) * HD + h];

  float G[NCH];
#pragma unroll
  for (int k = 0; k < NCH; ++k)
    G[k] = R[k] * Esuf[k] + (Tk[k] - R[k]) * E + R[k + 1] * Epre[k + 1];

  int id[NNOTE];
#pragma unroll
  for (int n = 0; n < NNOTE; ++n) id[n] = ids[n];

  float score[NNOTE] = {0.f, 0.f, 0.f, 0.f};
#pragma unroll
  for (int c = 0; c < NCH; ++c) {
    int cnt = 0;
#pragma unroll
    for (int n = 0; n < NNOTE; ++n) cnt += (id[n] + 1 <= c) ? 1 : 0;
    const float inv = (cnt > 0) ? (1.f / (float)cnt) : 0.f;
#pragma unroll
    for (int n = 0; n < NNOTE; ++n) {
      const float m = (cnt == 0) ? 0.25f : (((id[n] + 1) <= c) ? inv : 0.f);
      score[n] += m * G[c];
    }
  }
#pragma unroll
  for (int n = 0; n < NNOTE; ++n) {
    out[(size_t)n * HD + h] = 1.f / (1.f + expf(-score[n]));
  }
}

extern "C" void kernel_launch(void* const* d_in, const int* in_sizes, int n_in,
                              void* d_out, int out_size, void* d_ws, size_t ws_size,
                              hipStream_t stream) {
  (void)in_sizes; (void)n_in; (void)out_size; (void)ws_size;
  const float* enc = (const float*)d_in[0];       // (4096, 768)
  // d_in[1] = label_queries — provably unused (softmax over notes is
  // shift-invariant; the identical-across-notes score term cancels exactly).
  const float* lw  = (const float*)d_in[2];       // (768, 8921) buffer, read as (8921, 768)
  const int*   ids = (const int*)d_in[3];         // (4,) note_end_chunk_ids
  float* ws  = (float*)d_ws;                      // 256*768 floats = 786 KB used
  float* out = (float*)d_out;                     // (4, 768) fp32

  talc_reduce_kernel<<<NPART, 768, 0, stream>>>(enc, lw, ws);
  talc_finish_kernel<<<6, 128, 0, stream>>>(lw, ids, ws, out);
}

// Round 6
// 101.309 us; speedup vs baseline: 1.1935x; 1.0013x over previous
//
#include <hip/hip_runtime.h>
#include <math.h>

// Problem constants (fixed by the reference harness)
#define HD      768          // hidden dim H
#define TLEN    512          // seq_len T
#define NCH     8            // NC chunks
#define NNOTE   4            // NN notes
#define ROWK    1115         // full rows of reshaped-weights per chunk
#define F4      192          // HD/4 float4 per row

// Byte-balanced 256-block partition (all blocks 154-160 KB):
//   enc: 80 blocks = 8 chunks x 10 segs; segs 0..7 -> 51 rows, segs 8..9 -> 52 rows
//   lw : 176 blocks = 8 k x 22 segs;     segs 0..14 -> 51 rows, segs 15..21 -> 50 rows
#define ENC_BLOCKS  80
#define ENC_SEGS    10
#define LW_SEGS     22
#define LW_BLOCKS   176
#define NPART       256

// ---------------------------------------------------------------------------
// Kernel A: all the heavy memory traffic (40 MB). TLP ladder (measured):
// 3 waves/CU = ~8.5us-equiv, 6 waves = -2.33us, 12 waves = -0.71us.
// This round: 960 threads = 15 waves/CU, 5-way row split by residue class
// among five 192-thread groups; groups combine via 12 KB LDS; single P-row
// write per block unchanged, so kernel B stays byte-identical to the proven
// version. Same addresses, same coalescing, same partition.
// ---------------------------------------------------------------------------
#define NRG 5
__global__ __launch_bounds__(NRG * 192) void talc_reduce_kernel(
    const float* __restrict__ enc,
    const float* __restrict__ lw,
    float* __restrict__ ws) {
  const int t   = threadIdx.x;        // 0..959
  const int rg  = t / 192;            // row-residue group 0..4
  const int col = t - rg * 192;       // float4 column 0..191
  const int b = blockIdx.x;           // 0..255
  float4* P = (float4*)ws;            // P[256][192] float4

  const float4* base;
  int rn;
  if (b < ENC_BLOCKS) {
    const int c = b / ENC_SEGS, seg = b - c * ENC_SEGS;
    const int start = (seg < 8) ? 51 * seg : 408 + 52 * (seg - 8);
    rn = (seg < 8) ? 51 : 52;
    base = (const float4*)enc + (size_t)(c * TLEN + start) * F4 + col;
  } else {
    const int l = b - ENC_BLOCKS;
    const int k = l / LW_SEGS, seg = l - k * LW_SEGS;
    const int start = (seg < 15) ? 51 * seg : 765 + 50 * (seg - 15);
    rn = (seg < 15) ? 51 : 50;
    base = (const float4*)lw + (size_t)(k * ROWK + start) * F4 + col;
  }

  float4 acc = make_float4(0.f, 0.f, 0.f, 0.f);
#pragma unroll 4
  for (int r = rg; r < rn; r += NRG) {
    float4 v = base[(size_t)r * F4];
    acc.x += v.x; acc.y += v.y; acc.z += v.z; acc.w += v.w;
  }

  __shared__ float4 comb[NRG - 1][192];   // 12 KB
  if (rg != 0) comb[rg - 1][col] = acc;
  __syncthreads();
  if (rg == 0) {
#pragma unroll
    for (int g = 0; g < NRG - 1; ++g) {
      float4 o = comb[g][col];
      acc.x += o.x; acc.y += o.y; acc.z += o.z; acc.w += o.w;
    }
    P[(size_t)b * F4 + col] = acc;
  }
}

// ---------------------------------------------------------------------------
// Kernel B: finish (byte-identical to the proven R0/R2/R4/R5 version).
// 6 blocks x 128 threads, one thread per h.
//   B[c]  = sum of 10 enc partials      (512-block column sums of encoding)
//   Tk[k] = sum of 22 lw partials       (1115-row sums of reshaped weights)
//   R[m]  = lwR[1115*m, h], m=0..8      (boundary rows)
//   G[k]  = R[k]*Esuf[k] + (Tk[k]-R[k])*E + R[k+1]*Epre[k+1]
//   out[n,h] = sigmoid( sum_c Mc[n][c] * G[c] ),  Mc = note-mask softmax table
// ---------------------------------------------------------------------------
__global__ __launch_bounds__(128) void talc_finish_kernel(
    const float* __restrict__ lw,
    const int* __restrict__ ids,
    const float* __restrict__ ws,
    float* __restrict__ out) {
  const int h = blockIdx.x * 128 + threadIdx.x;   // 0..767
  if (h >= HD) return;
  const float* P = ws;

  float B[NCH];
#pragma unroll
  for (int c = 0; c < NCH; ++c) {
    float s = 0.f;
#pragma unroll
    for (int g = 0; g < ENC_SEGS; ++g) s += P[(size_t)(c * ENC_SEGS + g) * HD + h];
    B[c] = s;
  }
  float Esuf[NCH + 1];
  Esuf[NCH] = 0.f;
#pragma unroll
  for (int c = NCH - 1; c >= 0; --c) Esuf[c] = Esuf[c + 1] + B[c];
  float Epre[NCH + 1];
  Epre[0] = 0.f;
#pragma unroll
  for (int c = 1; c <= NCH; ++c) Epre[c] = Epre[c - 1] + B[c - 1];
  const float E = Esuf[0];

  float Tk[NCH];
#pragma unroll
  for (int k = 0; k < NCH; ++k) {
    float s = 0.f;
#pragma unroll
    for (int g = 0; g < LW_SEGS; ++g)
      s += P[(size_t)(ENC_BLOCKS + k * LW_SEGS + g) * HD + h];
    Tk[k] = s;
  }

  // single boundary rows R[m] = lwR[1115*m, h]
  float R[NCH + 1];
#pragma unroll
  for (int m = 0; m <= NCH; ++m) R[m] = lw[(size_t)(m * ROWK) * HD + h];

  float G[NCH];
#pragma unroll
  for (int k = 0; k < NCH; ++k)
    G[k] = R[k] * Esuf[k] + (Tk[k] - R[k]) * E + R[k + 1] * Epre[k + 1];

  int id[NNOTE];
#pragma unroll
  for (int n = 0; n < NNOTE; ++n) id[n] = ids[n];

  float score[NNOTE] = {0.f, 0.f, 0.f, 0.f};
#pragma unroll
  for (int c = 0; c < NCH; ++c) {
    int cnt = 0;
#pragma unroll
    for (int n = 0; n < NNOTE; ++n) cnt += (id[n] + 1 <= c) ? 1 : 0;
    const float inv = (cnt > 0) ? (1.f / (float)cnt) : 0.f;
#pragma unroll
    for (int n = 0; n < NNOTE; ++n) {
      const float m = (cnt == 0) ? 0.25f : (((id[n] + 1) <= c) ? inv : 0.f);
      score[n] += m * G[c];
    }
  }
#pragma unroll
  for (int n = 0; n < NNOTE; ++n) {
    out[(size_t)n * HD + h] = 1.f / (1.f + expf(-score[n]));
  }
}

extern "C" void kernel_launch(void* const* d_in, const int* in_sizes, int n_in,
                              void* d_out, int out_size, void* d_ws, size_t ws_size,
                              hipStream_t stream) {
  (void)in_sizes; (void)n_in; (void)out_size; (void)ws_size;
  const float* enc = (const float*)d_in[0];       // (4096, 768)
  // d_in[1] = label_queries — provably unused (softmax over notes is
  // shift-invariant; the identical-across-notes score term cancels exactly).
  const float* lw  = (const float*)d_in[2];       // (768, 8921) buffer, read as (8921, 768)
  const int*   ids = (const int*)d_in[3];         // (4,) note_end_chunk_ids
  float* ws  = (float*)d_ws;                      // 256*768 floats = 786 KB used
  float* out = (float*)d_out;                     // (4, 768) fp32

  talc_reduce_kernel<<<NPART, NRG * 192, 0, stream>>>(enc, lw, ws);
  talc_finish_kernel<<<6, 128, 0, stream>>>(lw, ids, ws, out);
}